// Round 5
// baseline (722.189 us; speedup 1.0000x reference)
//
#include <hip/hip_runtime.h>

// Problem constants
#define P_TOTAL 132096
#define NPOOL   4096
#define GDIM    1000
#define HDIM    150
#define MGRP    2048
#define KMAX    128

typedef __attribute__((ext_vector_type(4))) float f32x4;
typedef __attribute__((ext_vector_type(8))) short short8;
typedef __attribute__((ext_vector_type(4))) unsigned int u32x4;

// ---------- workspace layout (bytes) ----------
// w1ct  bf16[32][160][32]    327,680 @ 0
// w1abt bf16[32][320][32]    655,360 @ 327,680
// w2t   bf16[5][160][32]      51,200 @ 983,040
// abpre f32 [4096][320]    5,242,880 @ 1,034,240
// tabs  f32 [20][160]         12,800 @ 6,277,120
// sgrid f32 [2048][128]    1,048,576 @ 6,289,920
// gbf   bf16[4096][1024]   8,388,608 @ 7,338,496   -> total 15,727,104
#define OFF_W1CT   0
#define OFF_W1ABT  327680
#define OFF_W2T    983040
#define OFF_ABPRE  1034240
#define OFF_TABS   6277120
#define OFF_SGRID  6289920
#define OFF_GBF    7338496

__device__ __forceinline__ short f2bf(float f) {
  union { float f; unsigned u; } v; v.f = f;
  unsigned r = v.u + 0x7FFFu + ((v.u >> 16) & 1u);   // RNE
  return (short)(r >> 16);
}

// bf16 product of 8 packed bf16 pairs -> packed bf16 (truncating)
__device__ __forceinline__ short8 bfmul8(u32x4 m, u32x4 a) {
  union { short8 s; unsigned u[4]; } r;
  #pragma unroll
  for (int i = 0; i < 4; ++i) {
    float ml = __builtin_bit_cast(float, m[i] << 16);
    float mh = __builtin_bit_cast(float, m[i] & 0xFFFF0000u);
    float al = __builtin_bit_cast(float, a[i] << 16);
    float ah = __builtin_bit_cast(float, a[i] & 0xFFFF0000u);
    unsigned pl = __builtin_bit_cast(unsigned, ml * al);
    unsigned ph = __builtin_bit_cast(unsigned, mh * ah);
    r.u[i] = __builtin_amdgcn_perm(ph, pl, 0x07060302u);
  }
  return r.s;
}

// ---------- kernel 1: merged prep (weights->bf16, g_i->bf16, phi tables) ----------
#define PREP_W  (32*160*32 + 32*320*32 + 5*160*32)     // 517,120
#define PREP_G  (NPOOL*512)                            // 2,097,152 dwords
#define PREP_T  (20*160)                               // 3,200
__global__ __launch_bounds__(256) void prep_kernel(
    const float* __restrict__ W1, const float* __restrict__ W2,
    const float* __restrict__ g_i,
    const float* __restrict__ dist_emb, const float* __restrict__ genre_emb,
    const float* __restrict__ spk_emb, const float* __restrict__ b1,
    short* __restrict__ w1ct, short* __restrict__ w1abt, short* __restrict__ w2t,
    unsigned* __restrict__ gbf, float* __restrict__ tabs) {
  int idx = blockIdx.x * 256 + threadIdx.x;
  const int T1 = 32*160*32, T2 = 32*320*32, T3 = 5*160*32;
  if (idx < T1) {                               // W1c rows 2000..2999 -> [32][160][32]
    int c = idx / (160*32); int rem = idx % (160*32);
    int n = rem / 32, kk = rem % 32;
    int k = c*32 + kk;
    float v = (k < GDIM && n < HDIM) ? W1[(2000 + k)*HDIM + n] : 0.f;
    w1ct[idx] = f2bf(v);
  } else if (idx < T1 + T2) {                   // [W1a | W1b] -> [32][320][32]
    int i = idx - T1;
    int c = i / (320*32); int rem = i % (320*32);
    int n = rem / 32, kk = rem % 32;
    int k = c*32 + kk;
    float v = 0.f;
    if (k < GDIM) {
      if (n < HDIM)                 v = W1[k*HDIM + n];
      else if (n >= 160 && n < 310) v = W1[(1000 + k)*HDIM + (n - 160)];
    }
    w1abt[i] = f2bf(v);
  } else if (idx < PREP_W) {                    // W2 -> [5][160][32]
    int i = idx - T1 - T2;
    int c = i / (160*32); int rem = i % (160*32);
    int n = rem / 32, kk = rem % 32;
    int k = c*32 + kk;
    float v = (k < HDIM && n < HDIM) ? W2[k*HDIM + n] : 0.f;
    w2t[i] = f2bf(v);
  } else if (idx < PREP_W + PREP_G) {           // g_i -> bf16 [4096][1024], one dword=2 cols
    int i = idx - PREP_W;
    int row = i >> 9, jd = i & 511;
    int c0 = jd * 2;
    unsigned lo = 0, hi = 0;
    if (c0 < GDIM)     lo = (unsigned)(unsigned short)f2bf(g_i[row*GDIM + c0]);
    if (c0 + 1 < GDIM) hi = (unsigned)(unsigned short)f2bf(g_i[row*GDIM + c0 + 1]);
    gbf[i] = lo | (hi << 16);
  } else if (idx < PREP_W + PREP_G + PREP_T) {  // phi tables, b1 folded into dist rows
    int i = idx - PREP_W - PREP_G;
    int row = i / 160, n = i % 160;
    float acc = 0.f;
    if (n < HDIM) {
      const float* emb; int woff;
      if (row < 9)       { emb = dist_emb  + row*20;      woff = 3000; acc = b1[n]; }
      else if (row < 17) { emb = genre_emb + (row-9)*20;  woff = 3020; }
      else               { emb = spk_emb   + (row-17)*20; woff = 3040; }
      #pragma unroll
      for (int kk = 0; kk < 20; ++kk) acc += emb[kk] * W1[(woff + kk)*HDIM + n];
    }
    tabs[i] = acc;
  }
}

// ---------- kernel 2: abpre[4096][320](f32) = g_i @ [W1a|W1b] ----------
// grid (64, 4): 80 cols per block-col, 4 waves x 16 rows
__global__ __launch_bounds__(256) void pre_gemm_kernel(const unsigned short* __restrict__ gbf,
                                                       const short* __restrict__ w1abt,
                                                       float* __restrict__ abpre) {
  int wave = threadIdx.x >> 6, lane = threadIdx.x & 63;
  int quad = lane >> 4, n16 = lane & 15;
  int rowbase = blockIdx.x * 64 + wave * 16;
  int colbase = blockIdx.y * 80;

  f32x4 acc[5];
  #pragma unroll
  for (int t = 0; t < 5; ++t) acc[t] = (f32x4){0.f, 0.f, 0.f, 0.f};

  const unsigned short* arow = gbf + (long)(rowbase + n16) * 1024 + quad*8;

  for (int c = 0; c < 32; ++c) {
    short8 a = *(const short8*)(arow + c*32);
    const short* bp = w1abt + ((c*320 + colbase + n16) * 32 + quad*8);
    #pragma unroll
    for (int t = 0; t < 5; ++t) {
      short8 b = *(const short8*)(bp + t*16*32);
      acc[t] = __builtin_amdgcn_mfma_f32_16x16x32_bf16(a, b, acc[t], 0, 0, 0);
    }
  }
  #pragma unroll
  for (int t = 0; t < 5; ++t) {
    #pragma unroll
    for (int r = 0; r < 4; ++r) {
      int row = rowbase + quad*4 + r;
      abpre[(long)row * 320 + colbase + t*16 + n16] = acc[t][r];
    }
  }
}

// ---------- kernel 3: per-pair fused MLP + score scatter (natural order) ----------
// wave = 32 pairs (2 row-tiles of 16) x 160 cols; block = 4 waves = 128 pairs
__global__ __launch_bounds__(256) void pair_kernel(
    const unsigned short* __restrict__ gbf, const float* __restrict__ ms,
    const short* __restrict__ w1ct, const short* __restrict__ w2t,
    const float* __restrict__ abpre, const float* __restrict__ tabs,
    const float* __restrict__ b2, const float* __restrict__ W3,
    const float* __restrict__ b3,
    const int* __restrict__ mention_ids, const int* __restrict__ antecedent_ids,
    const int* __restrict__ dist_ids, const int* __restrict__ genre_ids,
    const int* __restrict__ spk_ids, const int* __restrict__ seg_ids,
    const int* __restrict__ offs, float* __restrict__ sgrid) {

  __shared__ __align__(16) short h1s[4][32*184];

  int wave = threadIdx.x >> 6, lane = threadIdx.x & 63;
  int quad = lane >> 4, n16 = lane & 15;
  int p0 = blockIdx.x * 128 + wave * 32;

  // per-lane A row pointers (natural pair order — coalesced id reads)
  int pm0 = p0 + n16, pm1 = p0 + 16 + n16;
  const unsigned short* pm0p = gbf + (long)mention_ids[pm0]    * 1024 + quad*8;
  const unsigned short* pa0p = gbf + (long)antecedent_ids[pm0] * 1024 + quad*8;
  const unsigned short* pm1p = gbf + (long)mention_ids[pm1]    * 1024 + quad*8;
  const unsigned short* pa1p = gbf + (long)antecedent_ids[pm1] * 1024 + quad*8;

  f32x4 acc0[10], acc1[10];
  #pragma unroll
  for (int t = 0; t < 10; ++t) {
    acc0[t] = (f32x4){0.f, 0.f, 0.f, 0.f};
    acc1[t] = (f32x4){0.f, 0.f, 0.f, 0.f};
  }

  // depth-2 prefetch, all named registers, unroll-by-2
  u32x4 M0a = *(const u32x4*)(pm0p);       u32x4 M1a = *(const u32x4*)(pm1p);
  u32x4 A0a = *(const u32x4*)(pa0p);       u32x4 A1a = *(const u32x4*)(pa1p);
  u32x4 M0b = *(const u32x4*)(pm0p + 32);  u32x4 M1b = *(const u32x4*)(pm1p + 32);
  u32x4 A0b = *(const u32x4*)(pa0p + 32);  u32x4 A1b = *(const u32x4*)(pa1p + 32);

  for (int c = 0; c < 32; c += 2) {
    {
      short8 f0 = bfmul8(M0a, A0a);
      short8 f1 = bfmul8(M1a, A1a);
      if (c < 30) {
        M0a = *(const u32x4*)(pm0p + (c+2)*32);
        M1a = *(const u32x4*)(pm1p + (c+2)*32);
        A0a = *(const u32x4*)(pa0p + (c+2)*32);
        A1a = *(const u32x4*)(pa1p + (c+2)*32);
      }
      const short* bp = w1ct + ((c*160 + n16) * 32 + quad*8);
      #pragma unroll
      for (int t = 0; t < 10; ++t) {
        short8 b = *(const short8*)(bp + t*16*32);
        acc0[t] = __builtin_amdgcn_mfma_f32_16x16x32_bf16(f0, b, acc0[t], 0, 0, 0);
        acc1[t] = __builtin_amdgcn_mfma_f32_16x16x32_bf16(f1, b, acc1[t], 0, 0, 0);
      }
    }
    {
      short8 f0 = bfmul8(M0b, A0b);
      short8 f1 = bfmul8(M1b, A1b);
      if (c < 30) {
        M0b = *(const u32x4*)(pm0p + (c+3)*32);
        M1b = *(const u32x4*)(pm1p + (c+3)*32);
        A0b = *(const u32x4*)(pa0p + (c+3)*32);
        A1b = *(const u32x4*)(pa1p + (c+3)*32);
      }
      const short* bp = w1ct + (((c+1)*160 + n16) * 32 + quad*8);
      #pragma unroll
      for (int t = 0; t < 10; ++t) {
        short8 b = *(const short8*)(bp + t*16*32);
        acc0[t] = __builtin_amdgcn_mfma_f32_16x16x32_bf16(f0, b, acc0[t], 0, 0, 0);
        acc1[t] = __builtin_amdgcn_mfma_f32_16x16x32_bf16(f1, b, acc1[t], 0, 0, 0);
      }
    }
  }

  // ---- epilogue 1: add precomputed terms, relu, stash h1 (bf16) in LDS ----
  int idm0[4], ida0[4], idm1[4], ida1[4];
  int idd0[4], idg0[4], ids0[4], idd1[4], idg1[4], ids1[4];
  #pragma unroll
  for (int r = 0; r < 4; ++r) {
    int pr0 = p0 + quad*4 + r;
    int pr1 = p0 + 16 + quad*4 + r;
    idm0[r] = mention_ids[pr0];    idm1[r] = mention_ids[pr1];
    ida0[r] = antecedent_ids[pr0]; ida1[r] = antecedent_ids[pr1];
    idd0[r] = dist_ids[pr0];       idd1[r] = dist_ids[pr1];
    idg0[r] = genre_ids[pr0];      idg1[r] = genre_ids[pr1];
    ids0[r] = spk_ids[pr0];        ids1[r] = spk_ids[pr1];
  }
  const float* Dd = tabs;             // 9 x 160 (includes b1)
  const float* Ge = tabs + 9*160;     // 8 x 160
  const float* Se = tabs + 17*160;    // 3 x 160

  #pragma unroll
  for (int t = 0; t < 10; ++t) {
    int n = t*16 + n16;
    #pragma unroll
    for (int r = 0; r < 4; ++r) {
      float v0 = acc0[t][r]
               + abpre[(long)idm0[r]*320 + n]
               + abpre[(long)ida0[r]*320 + 160 + n]
               + Dd[idd0[r]*160 + n] + Ge[idg0[r]*160 + n] + Se[ids0[r]*160 + n];
      float v1 = acc1[t][r]
               + abpre[(long)idm1[r]*320 + n]
               + abpre[(long)ida1[r]*320 + 160 + n]
               + Dd[idd1[r]*160 + n] + Ge[idg1[r]*160 + n] + Se[ids1[r]*160 + n];
      h1s[wave][(quad*4 + r)*184 + n]      = f2bf(fmaxf(v0, 0.f));
      h1s[wave][(16 + quad*4 + r)*184 + n] = f2bf(fmaxf(v1, 0.f));
    }
  }
  // wave-private LDS slice: in-wave ordering via lgkmcnt, no barrier needed

  // ---- layer 2 + 3 per tile ----
  float bias3 = b3[0];
  float w3v[10], b2v[10];
  #pragma unroll
  for (int t = 0; t < 10; ++t) {
    int n = t*16 + n16;
    w3v[t] = (n < HDIM) ? W3[n] : 0.f;
    b2v[t] = (n < HDIM) ? b2[n] : 0.f;
  }

  #pragma unroll
  for (int tile = 0; tile < 2; ++tile) {
    f32x4 acc2[10];
    #pragma unroll
    for (int t = 0; t < 10; ++t) acc2[t] = (f32x4){0.f, 0.f, 0.f, 0.f};

    #pragma unroll
    for (int c = 0; c < 5; ++c) {
      short8 a = *(const short8*)(&h1s[wave][(tile*16 + n16)*184 + c*32 + quad*8]);
      const short* bp = w2t + ((c*160 + n16) * 32 + quad*8);
      #pragma unroll
      for (int t = 0; t < 10; ++t) {
        short8 b = *(const short8*)(bp + t*16*32);
        acc2[t] = __builtin_amdgcn_mfma_f32_16x16x32_bf16(a, b, acc2[t], 0, 0, 0);
      }
    }

    float part[4] = {0.f, 0.f, 0.f, 0.f};
    #pragma unroll
    for (int t = 0; t < 10; ++t) {
      #pragma unroll
      for (int r = 0; r < 4; ++r) {
        float h2 = fmaxf(acc2[t][r] + b2v[t], 0.f);
        part[r] += h2 * w3v[t];
      }
    }
    for (int msk = 1; msk < 16; msk <<= 1) {
      #pragma unroll
      for (int r = 0; r < 4; ++r) part[r] += __shfl_xor(part[r], msk);
    }

    if (n16 == 0) {
      #pragma unroll
      for (int r = 0; r < 4; ++r) {
        int pr = p0 + tile*16 + quad*4 + r;
        int im = tile ? idm1[r] : idm0[r];
        int ia = tile ? ida1[r] : ida0[r];
        float sc = part[r] + bias3 + ms[im] + ms[ia];
        sgrid[seg_ids[pr] * KMAX + offs[pr]] = sc;
      }
    }
  }
}

// ---------- kernel 4: per-group softmax (+epsilon) and full output fill ----------
__global__ __launch_bounds__(128) void softmax_kernel(const float* __restrict__ sgrid,
                                                      const int* __restrict__ lengths,
                                                      float* __restrict__ out) {
  int b = blockIdx.x, t = threadIdx.x;   // 128 threads
  if (b == 0) {
    out[t] = (t == 0) ? 1.0f : 1000.0f;
    if (t == 0) out[128] = 1000.0f;
    return;
  }
  int m = b - 1;
  int len = lengths[m];
  float s = (t < len) ? sgrid[m * KMAX + t] : -1e30f;

  __shared__ float redA[2];
  __shared__ float redB[2];

  float v = s;
  #pragma unroll
  for (int o = 32; o >= 1; o >>= 1) v = fmaxf(v, __shfl_xor(v, o));
  if ((t & 63) == 0) redA[t >> 6] = v;
  __syncthreads();
  float mx = fmaxf(fmaxf(redA[0], redA[1]), 0.0f);

  float e = (t < len) ? expf(s - mx) : 0.f;
  float sum = e;
  #pragma unroll
  for (int o = 32; o >= 1; o >>= 1) sum += __shfl_xor(sum, o);
  if ((t & 63) == 0) redB[t >> 6] = sum;
  __syncthreads();

  float eps_e = expf(-mx);
  float denom = redB[0] + redB[1] + eps_e;

  float* row = out + (long)(m + 1) * 129;
  float val;
  if (t < len)       val = e / denom;
  else if (t == len) val = eps_e / denom;
  else               val = 1000.0f;
  row[t] = val;
  if (t == 0) row[128] = (len == KMAX) ? (eps_e / denom) : 1000.0f;
}

extern "C" void kernel_launch(void* const* d_in, const int* in_sizes, int n_in,
                              void* d_out, int out_size, void* d_ws, size_t ws_size,
                              hipStream_t stream) {
  const float* g_i        = (const float*)d_in[0];
  const float* ms         = (const float*)d_in[1];
  const float* dist_emb   = (const float*)d_in[2];
  const float* genre_emb  = (const float*)d_in[3];
  const float* spk_emb    = (const float*)d_in[4];
  const float* W1         = (const float*)d_in[5];
  const float* b1         = (const float*)d_in[6];
  const float* W2         = (const float*)d_in[7];
  const float* b2         = (const float*)d_in[8];
  const float* W3         = (const float*)d_in[9];
  const float* b3         = (const float*)d_in[10];
  const int* mention_ids    = (const int*)d_in[11];
  const int* antecedent_ids = (const int*)d_in[12];
  const int* dist_ids       = (const int*)d_in[13];
  const int* genre_ids      = (const int*)d_in[14];
  const int* spk_ids        = (const int*)d_in[15];
  const int* lengths        = (const int*)d_in[16];
  const int* seg_ids        = (const int*)d_in[17];
  const int* offsets        = (const int*)d_in[18];

  char* ws = (char*)d_ws;
  short* w1ct   = (short*)(ws + OFF_W1CT);
  short* w1abt  = (short*)(ws + OFF_W1ABT);
  short* w2t    = (short*)(ws + OFF_W2T);
  float* abpre  = (float*)(ws + OFF_ABPRE);
  float* tabs   = (float*)(ws + OFF_TABS);
  float* sgrid  = (float*)(ws + OFF_SGRID);
  unsigned short* gbf = (unsigned short*)(ws + OFF_GBF);

  const int prepN = PREP_W + PREP_G + PREP_T;
  prep_kernel<<<(prepN + 255)/256, 256, 0, stream>>>(W1, W2, g_i,
                                                     dist_emb, genre_emb, spk_emb, b1,
                                                     w1ct, w1abt, w2t,
                                                     (unsigned*)gbf, tabs);
  dim3 gpre(NPOOL/64, 4);
  pre_gemm_kernel<<<gpre, 256, 0, stream>>>(gbf, w1abt, abpre);
  pair_kernel<<<P_TOTAL/128, 256, 0, stream>>>(gbf, ms, w1ct, w2t, abpre, tabs,
                                               b2, W3, b3,
                                               mention_ids, antecedent_ids,
                                               dist_ids, genre_ids, spk_ids,
                                               seg_ids, offsets, sgrid);
  softmax_kernel<<<MGRP + 1, 128, 0, stream>>>(sgrid, lengths, (float*)d_out);
}

// Round 6
// 356.221 us; speedup vs baseline: 2.0274x; 2.0274x over previous
//
#include <hip/hip_runtime.h>

// Problem constants
#define P_TOTAL 132096
#define NPOOL   4096
#define GDIM    1000
#define HDIM    150
#define MGRP    2048
#define KMAX    128

typedef __attribute__((ext_vector_type(4))) float f32x4;
typedef __attribute__((ext_vector_type(2))) float f32x2;
typedef __attribute__((ext_vector_type(8))) short short8;
typedef __attribute__((ext_vector_type(2))) unsigned int u32x2;

// ---------- workspace layout (bytes) ----------
// w1ct  bf16[32][160][32]    327,680 @ 0
// w1abt bf16[32][320][32]    655,360 @ 327,680
// w2t   bf16[5][160][32]      51,200 @ 983,040
// abpre f32 [4096][320]    5,242,880 @ 1,034,240
// tabs  f32 [20][160]         12,800 @ 6,277,120
// sgrid f32 [2048][128]    1,048,576 @ 6,289,920
// gf8   fp8 [4096][1024]   4,194,304 @ 7,338,496   (e4m3, zero-padded cols 1000..1023)
#define OFF_W1CT   0
#define OFF_W1ABT  327680
#define OFF_W2T    983040
#define OFF_ABPRE  1034240
#define OFF_TABS   6277120
#define OFF_SGRID  6289920
#define OFF_GF8    7338496

__device__ __forceinline__ short f2bf(float f) {
  union { float f; unsigned u; } v; v.f = f;
  unsigned r = v.u + 0x7FFFu + ((v.u >> 16) & 1u);   // RNE
  return (short)(r >> 16);
}

// truncating bf16 pack: one v_perm_b32 per 2 floats
__device__ __forceinline__ short8 pack8t(f32x4 a, f32x4 b) {
  union { f32x4 f; unsigned u[4]; } ua, ub; ua.f = a; ub.f = b;
  union { short8 s; unsigned u[4]; } r;
  r.u[0] = __builtin_amdgcn_perm(ua.u[1], ua.u[0], 0x07060302u);
  r.u[1] = __builtin_amdgcn_perm(ua.u[3], ua.u[2], 0x07060302u);
  r.u[2] = __builtin_amdgcn_perm(ub.u[1], ub.u[0], 0x07060302u);
  r.u[3] = __builtin_amdgcn_perm(ub.u[3], ub.u[2], 0x07060302u);
  return r.s;
}

// 8 fp8 x 8 fp8 -> elementwise product packed as 8 bf16 (HW cvt + pk mul + perm)
__device__ __forceinline__ short8 fp8mul8(u32x2 m, u32x2 a) {
  f32x2 m0 = __builtin_amdgcn_cvt_pk_f32_fp8(m[0], false);
  f32x2 m1 = __builtin_amdgcn_cvt_pk_f32_fp8(m[0], true);
  f32x2 m2 = __builtin_amdgcn_cvt_pk_f32_fp8(m[1], false);
  f32x2 m3 = __builtin_amdgcn_cvt_pk_f32_fp8(m[1], true);
  f32x2 a0 = __builtin_amdgcn_cvt_pk_f32_fp8(a[0], false);
  f32x2 a1 = __builtin_amdgcn_cvt_pk_f32_fp8(a[0], true);
  f32x2 a2 = __builtin_amdgcn_cvt_pk_f32_fp8(a[1], false);
  f32x2 a3 = __builtin_amdgcn_cvt_pk_f32_fp8(a[1], true);
  f32x2 p0 = m0 * a0, p1 = m1 * a1, p2 = m2 * a2, p3 = m3 * a3;
  union { short8 s; unsigned u[4]; } r;
  r.u[0] = __builtin_amdgcn_perm(__builtin_bit_cast(unsigned, p0[1]),
                                 __builtin_bit_cast(unsigned, p0[0]), 0x07060302u);
  r.u[1] = __builtin_amdgcn_perm(__builtin_bit_cast(unsigned, p1[1]),
                                 __builtin_bit_cast(unsigned, p1[0]), 0x07060302u);
  r.u[2] = __builtin_amdgcn_perm(__builtin_bit_cast(unsigned, p2[1]),
                                 __builtin_bit_cast(unsigned, p2[0]), 0x07060302u);
  r.u[3] = __builtin_amdgcn_perm(__builtin_bit_cast(unsigned, p3[1]),
                                 __builtin_bit_cast(unsigned, p3[0]), 0x07060302u);
  return r.s;
}

// ---------- kernel 1: merged prep (weights->bf16, g_i->fp8, phi tables) ----------
#define PREP_W  (32*160*32 + 32*320*32 + 5*160*32)     // 517,120
#define PREP_F8 (NPOOL*256)                            // 1,048,576 dwords (4 fp8 each)
#define PREP_T  (20*160)                               // 3,200
__global__ __launch_bounds__(256) void prep_kernel(
    const float* __restrict__ W1, const float* __restrict__ W2,
    const float* __restrict__ g_i,
    const float* __restrict__ dist_emb, const float* __restrict__ genre_emb,
    const float* __restrict__ spk_emb, const float* __restrict__ b1,
    short* __restrict__ w1ct, short* __restrict__ w1abt, short* __restrict__ w2t,
    unsigned* __restrict__ gf8, float* __restrict__ tabs) {
  int idx = blockIdx.x * 256 + threadIdx.x;
  const int T1 = 32*160*32, T2 = 32*320*32;
  if (idx < T1) {                               // W1c rows 2000..2999 -> [32][160][32]
    int c = idx / (160*32); int rem = idx % (160*32);
    int n = rem / 32, kk = rem % 32;
    int k = c*32 + kk;
    float v = (k < GDIM && n < HDIM) ? W1[(2000 + k)*HDIM + n] : 0.f;
    w1ct[idx] = f2bf(v);
  } else if (idx < T1 + T2) {                   // [W1a | W1b] -> [32][320][32]
    int i = idx - T1;
    int c = i / (320*32); int rem = i % (320*32);
    int n = rem / 32, kk = rem % 32;
    int k = c*32 + kk;
    float v = 0.f;
    if (k < GDIM) {
      if (n < HDIM)                 v = W1[k*HDIM + n];
      else if (n >= 160 && n < 310) v = W1[(1000 + k)*HDIM + (n - 160)];
    }
    w1abt[i] = f2bf(v);
  } else if (idx < PREP_W) {                    // W2 -> [5][160][32]
    int i = idx - T1 - T2;
    int c = i / (160*32); int rem = i % (160*32);
    int n = rem / 32, kk = rem % 32;
    int k = c*32 + kk;
    float v = (k < HDIM && n < HDIM) ? W2[k*HDIM + n] : 0.f;
    w2t[i] = f2bf(v);
  } else if (idx < PREP_W + PREP_F8) {          // g_i -> fp8 [4096][1024], dword = 4 cols
    int i = idx - PREP_W;
    int row = i >> 8, jd = i & 255;
    int c0 = jd * 4;
    float f0 = (c0     < GDIM) ? g_i[row*GDIM + c0]     : 0.f;
    float f1 = (c0 + 1 < GDIM) ? g_i[row*GDIM + c0 + 1] : 0.f;
    float f2 = (c0 + 2 < GDIM) ? g_i[row*GDIM + c0 + 2] : 0.f;
    float f3 = (c0 + 3 < GDIM) ? g_i[row*GDIM + c0 + 3] : 0.f;
    int d = 0;
    d = __builtin_amdgcn_cvt_pk_fp8_f32(f0, f1, d, false);   // bytes 0,1
    d = __builtin_amdgcn_cvt_pk_fp8_f32(f2, f3, d, true);    // bytes 2,3
    gf8[i] = (unsigned)d;
  } else if (idx < PREP_W + PREP_F8 + PREP_T) { // phi tables, b1 folded into dist rows
    int i = idx - PREP_W - PREP_F8;
    int row = i / 160, n = i % 160;
    float acc = 0.f;
    if (n < HDIM) {
      const float* emb; int woff;
      if (row < 9)       { emb = dist_emb  + row*20;      woff = 3000; acc = b1[n]; }
      else if (row < 17) { emb = genre_emb + (row-9)*20;  woff = 3020; }
      else               { emb = spk_emb   + (row-17)*20; woff = 3040; }
      #pragma unroll
      for (int kk = 0; kk < 20; ++kk) acc += emb[kk] * W1[(woff + kk)*HDIM + n];
    }
    tabs[i] = acc;
  }
}

// ---------- kernel 2: abpre[4096][320](f32) = g_i @ [W1a|W1b] ----------
// grid (64, 4): 80 cols per block-col, 4 waves x 16 rows; reads g_i f32 (coalesced)
__global__ __launch_bounds__(256) void pre_gemm_kernel(const float* __restrict__ g_i,
                                                       const short* __restrict__ w1abt,
                                                       float* __restrict__ abpre) {
  int wave = threadIdx.x >> 6, lane = threadIdx.x & 63;
  int quad = lane >> 4, n16 = lane & 15;
  int rowbase = blockIdx.x * 64 + wave * 16;
  int colbase = blockIdx.y * 80;

  f32x4 acc[5];
  #pragma unroll
  for (int t = 0; t < 5; ++t) acc[t] = (f32x4){0.f, 0.f, 0.f, 0.f};

  const float* arow = g_i + (long)(rowbase + n16) * GDIM;

  for (int c = 0; c < 32; ++c) {
    int k = c*32 + quad*8;
    short8 a;
    if (k < GDIM) {
      f32x4 x0 = *(const f32x4*)(arow + k);
      f32x4 x1 = *(const f32x4*)(arow + k + 4);
      a = pack8t(x0, x1);
    } else {
      a = (short8){0,0,0,0,0,0,0,0};
    }
    const short* bp = w1abt + ((c*320 + colbase + n16) * 32 + quad*8);
    #pragma unroll
    for (int t = 0; t < 5; ++t) {
      short8 b = *(const short8*)(bp + t*16*32);
      acc[t] = __builtin_amdgcn_mfma_f32_16x16x32_bf16(a, b, acc[t], 0, 0, 0);
    }
  }
  #pragma unroll
  for (int t = 0; t < 5; ++t) {
    #pragma unroll
    for (int r = 0; r < 4; ++r) {
      int row = rowbase + quad*4 + r;
      abpre[(long)row * 320 + colbase + t*16 + n16] = acc[t][r];
    }
  }
}

// ---------- kernel 3: per-pair fused MLP + score scatter ----------
// wave = 32 pairs (2 row-tiles of 16) x 160 cols; block = 4 waves = 128 pairs
// K-loop shape is EXACTLY r3's (depth-1 consume->reload->MFMA) — proven best.
__global__ __launch_bounds__(256) void pair_kernel(
    const unsigned char* __restrict__ gf8, const float* __restrict__ ms,
    const short* __restrict__ w1ct, const short* __restrict__ w2t,
    const float* __restrict__ abpre, const float* __restrict__ tabs,
    const float* __restrict__ b2, const float* __restrict__ W3,
    const float* __restrict__ b3,
    const int* __restrict__ mention_ids, const int* __restrict__ antecedent_ids,
    const int* __restrict__ dist_ids, const int* __restrict__ genre_ids,
    const int* __restrict__ spk_ids, const int* __restrict__ seg_ids,
    const int* __restrict__ offs, float* __restrict__ sgrid) {

  __shared__ __align__(16) short h1s[4][32*184];

  int wave = threadIdx.x >> 6, lane = threadIdx.x & 63;
  int quad = lane >> 4, n16 = lane & 15;
  int p0 = blockIdx.x * 128 + wave * 32;

  // per-lane A row pointers into the 4 MB fp8 table (L2-resident)
  int pm0 = p0 + n16, pm1 = p0 + 16 + n16;
  const unsigned char* pm0p = gf8 + (long)mention_ids[pm0]    * 1024 + quad*8;
  const unsigned char* pa0p = gf8 + (long)antecedent_ids[pm0] * 1024 + quad*8;
  const unsigned char* pm1p = gf8 + (long)mention_ids[pm1]    * 1024 + quad*8;
  const unsigned char* pa1p = gf8 + (long)antecedent_ids[pm1] * 1024 + quad*8;

  f32x4 acc0[10], acc1[10];
  #pragma unroll
  for (int t = 0; t < 10; ++t) {
    acc0[t] = (f32x4){0.f, 0.f, 0.f, 0.f};
    acc1[t] = (f32x4){0.f, 0.f, 0.f, 0.f};
  }

  // depth-1 named-register pipeline (r3 shape)
  u32x2 M0 = *(const u32x2*)(pm0p);
  u32x2 A0 = *(const u32x2*)(pa0p);
  u32x2 M1 = *(const u32x2*)(pm1p);
  u32x2 A1 = *(const u32x2*)(pa1p);

  for (int c = 0; c < 32; ++c) {
    short8 f0 = fp8mul8(M0, A0);
    short8 f1 = fp8mul8(M1, A1);
    if (c < 31) {
      M0 = *(const u32x2*)(pm0p + (c+1)*32);
      A0 = *(const u32x2*)(pa0p + (c+1)*32);
      M1 = *(const u32x2*)(pm1p + (c+1)*32);
      A1 = *(const u32x2*)(pa1p + (c+1)*32);
    }
    const short* bp = w1ct + ((c*160 + n16) * 32 + quad*8);
    #pragma unroll
    for (int t = 0; t < 10; ++t) {
      short8 b = *(const short8*)(bp + t*16*32);
      acc0[t] = __builtin_amdgcn_mfma_f32_16x16x32_bf16(f0, b, acc0[t], 0, 0, 0);
      acc1[t] = __builtin_amdgcn_mfma_f32_16x16x32_bf16(f1, b, acc1[t], 0, 0, 0);
    }
  }

  // ---- epilogue 1: add precomputed terms, relu, stash h1 (bf16) in LDS ----
  int idm0[4], ida0[4], idm1[4], ida1[4];
  int idd0[4], idg0[4], ids0[4], idd1[4], idg1[4], ids1[4];
  #pragma unroll
  for (int r = 0; r < 4; ++r) {
    int pr0 = p0 + quad*4 + r;
    int pr1 = p0 + 16 + quad*4 + r;
    idm0[r] = mention_ids[pr0];    idm1[r] = mention_ids[pr1];
    ida0[r] = antecedent_ids[pr0]; ida1[r] = antecedent_ids[pr1];
    idd0[r] = dist_ids[pr0];       idd1[r] = dist_ids[pr1];
    idg0[r] = genre_ids[pr0];      idg1[r] = genre_ids[pr1];
    ids0[r] = spk_ids[pr0];        ids1[r] = spk_ids[pr1];
  }
  const float* Dd = tabs;             // 9 x 160 (includes b1)
  const float* Ge = tabs + 9*160;     // 8 x 160
  const float* Se = tabs + 17*160;    // 3 x 160

  #pragma unroll
  for (int t = 0; t < 10; ++t) {
    int n = t*16 + n16;
    #pragma unroll
    for (int r = 0; r < 4; ++r) {
      float v0 = acc0[t][r]
               + abpre[(long)idm0[r]*320 + n]
               + abpre[(long)ida0[r]*320 + 160 + n]
               + Dd[idd0[r]*160 + n] + Ge[idg0[r]*160 + n] + Se[ids0[r]*160 + n];
      float v1 = acc1[t][r]
               + abpre[(long)idm1[r]*320 + n]
               + abpre[(long)ida1[r]*320 + 160 + n]
               + Dd[idd1[r]*160 + n] + Ge[idg1[r]*160 + n] + Se[ids1[r]*160 + n];
      h1s[wave][(quad*4 + r)*184 + n]      = f2bf(fmaxf(v0, 0.f));
      h1s[wave][(16 + quad*4 + r)*184 + n] = f2bf(fmaxf(v1, 0.f));
    }
  }
  // wave-private LDS slice: in-wave ordering via lgkmcnt, no barrier needed

  // ---- layer 2 + 3 per tile ----
  float bias3 = b3[0];
  float w3v[10], b2v[10];
  #pragma unroll
  for (int t = 0; t < 10; ++t) {
    int n = t*16 + n16;
    w3v[t] = (n < HDIM) ? W3[n] : 0.f;
    b2v[t] = (n < HDIM) ? b2[n] : 0.f;
  }

  #pragma unroll
  for (int tile = 0; tile < 2; ++tile) {
    f32x4 acc2[10];
    #pragma unroll
    for (int t = 0; t < 10; ++t) acc2[t] = (f32x4){0.f, 0.f, 0.f, 0.f};

    #pragma unroll
    for (int c = 0; c < 5; ++c) {
      short8 a = *(const short8*)(&h1s[wave][(tile*16 + n16)*184 + c*32 + quad*8]);
      const short* bp = w2t + ((c*160 + n16) * 32 + quad*8);
      #pragma unroll
      for (int t = 0; t < 10; ++t) {
        short8 b = *(const short8*)(bp + t*16*32);
        acc2[t] = __builtin_amdgcn_mfma_f32_16x16x32_bf16(a, b, acc2[t], 0, 0, 0);
      }
    }

    float part[4] = {0.f, 0.f, 0.f, 0.f};
    #pragma unroll
    for (int t = 0; t < 10; ++t) {
      #pragma unroll
      for (int r = 0; r < 4; ++r) {
        float h2 = fmaxf(acc2[t][r] + b2v[t], 0.f);
        part[r] += h2 * w3v[t];
      }
    }
    for (int msk = 1; msk < 16; msk <<= 1) {
      #pragma unroll
      for (int r = 0; r < 4; ++r) part[r] += __shfl_xor(part[r], msk);
    }

    if (n16 == 0) {
      #pragma unroll
      for (int r = 0; r < 4; ++r) {
        int pr = p0 + tile*16 + quad*4 + r;
        int im = tile ? idm1[r] : idm0[r];
        int ia = tile ? ida1[r] : ida0[r];
        float sc = part[r] + bias3 + ms[im] + ms[ia];
        sgrid[seg_ids[pr] * KMAX + offs[pr]] = sc;
      }
    }
  }
}

// ---------- kernel 4: per-group softmax (+epsilon) and full output fill ----------
__global__ __launch_bounds__(128) void softmax_kernel(const float* __restrict__ sgrid,
                                                      const int* __restrict__ lengths,
                                                      float* __restrict__ out) {
  int b = blockIdx.x, t = threadIdx.x;   // 128 threads
  if (b == 0) {
    out[t] = (t == 0) ? 1.0f : 1000.0f;
    if (t == 0) out[128] = 1000.0f;
    return;
  }
  int m = b - 1;
  int len = lengths[m];
  float s = (t < len) ? sgrid[m * KMAX + t] : -1e30f;

  __shared__ float redA[2];
  __shared__ float redB[2];

  float v = s;
  #pragma unroll
  for (int o = 32; o >= 1; o >>= 1) v = fmaxf(v, __shfl_xor(v, o));
  if ((t & 63) == 0) redA[t >> 6] = v;
  __syncthreads();
  float mx = fmaxf(fmaxf(redA[0], redA[1]), 0.0f);

  float e = (t < len) ? expf(s - mx) : 0.f;
  float sum = e;
  #pragma unroll
  for (int o = 32; o >= 1; o >>= 1) sum += __shfl_xor(sum, o);
  if ((t & 63) == 0) redB[t >> 6] = sum;
  __syncthreads();

  float eps_e = expf(-mx);
  float denom = redB[0] + redB[1] + eps_e;

  float* row = out + (long)(m + 1) * 129;
  float val;
  if (t < len)       val = e / denom;
  else if (t == len) val = eps_e / denom;
  else               val = 1000.0f;
  row[t] = val;
  if (t == 0) row[128] = (len == KMAX) ? (eps_e / denom) : 1000.0f;
}

extern "C" void kernel_launch(void* const* d_in, const int* in_sizes, int n_in,
                              void* d_out, int out_size, void* d_ws, size_t ws_size,
                              hipStream_t stream) {
  const float* g_i        = (const float*)d_in[0];
  const float* ms         = (const float*)d_in[1];
  const float* dist_emb   = (const float*)d_in[2];
  const float* genre_emb  = (const float*)d_in[3];
  const float* spk_emb    = (const float*)d_in[4];
  const float* W1         = (const float*)d_in[5];
  const float* b1         = (const float*)d_in[6];
  const float* W2         = (const float*)d_in[7];
  const float* b2         = (const float*)d_in[8];
  const float* W3         = (const float*)d_in[9];
  const float* b3         = (const float*)d_in[10];
  const int* mention_ids    = (const int*)d_in[11];
  const int* antecedent_ids = (const int*)d_in[12];
  const int* dist_ids       = (const int*)d_in[13];
  const int* genre_ids      = (const int*)d_in[14];
  const int* spk_ids        = (const int*)d_in[15];
  const int* lengths        = (const int*)d_in[16];
  const int* seg_ids        = (const int*)d_in[17];
  const int* offsets        = (const int*)d_in[18];

  char* ws = (char*)d_ws;
  short* w1ct   = (short*)(ws + OFF_W1CT);
  short* w1abt  = (short*)(ws + OFF_W1ABT);
  short* w2t    = (short*)(ws + OFF_W2T);
  float* abpre  = (float*)(ws + OFF_ABPRE);
  float* tabs   = (float*)(ws + OFF_TABS);
  float* sgrid  = (float*)(ws + OFF_SGRID);
  unsigned char* gf8 = (unsigned char*)(ws + OFF_GF8);

  const int prepN = PREP_W + PREP_F8 + PREP_T;
  prep_kernel<<<(prepN + 255)/256, 256, 0, stream>>>(W1, W2, g_i,
                                                     dist_emb, genre_emb, spk_emb, b1,
                                                     w1ct, w1abt, w2t,
                                                     (unsigned*)gf8, tabs);
  dim3 gpre(NPOOL/64, 4);
  pre_gemm_kernel<<<gpre, 256, 0, stream>>>(g_i, w1abt, abpre);
  pair_kernel<<<P_TOTAL/128, 256, 0, stream>>>(gf8, ms, w1ct, w2t, abpre, tabs,
                                               b2, W3, b3,
                                               mention_ids, antecedent_ids,
                                               dist_ids, genre_ids, spk_ids,
                                               seg_ids, offsets, sgrid);
  softmax_kernel<<<MGRP + 1, 128, 0, stream>>>(sgrid, lengths, (float*)d_out);
}